// Round 14
// baseline (391.263 us; speedup 1.0000x reference)
//
#include <hip/hip_runtime.h>

#define HID 128
#define SCAN_B 256

__device__ __forceinline__ float bf_lo(unsigned int u) { return __uint_as_float(u << 16); }
__device__ __forceinline__ float bf_hi(unsigned int u) { return __uint_as_float(u & 0xFFFF0000u); }
__device__ __forceinline__ unsigned short f2bf(float f) {
    unsigned int u = __float_as_uint(f);
    unsigned int r = (u + 0x7FFFu + ((u >> 16) & 1u)) >> 16;
    return (unsigned short)r;
}

// ---------------- init: detect index dtype (1 thread) + zero deg (grid-stride) ----------
__global__ void init_kernel(const unsigned int* __restrict__ p, int* __restrict__ flag,
                            float4* __restrict__ deg4, long long n4) {
    if (blockIdx.x == 0 && threadIdx.x == 0) {
        int is64 = 1;
        for (int i = 0; i < 64; ++i) {
            if (p[2 * i + 1] != 0u) { is64 = 0; break; }
        }
        *flag = is64;
    }
    long long i = (long long)blockIdx.x * blockDim.x + threadIdx.x;
    long long stride = (long long)gridDim.x * blockDim.x;
    for (; i < n4; i += stride) deg4[i] = make_float4(0.f, 0.f, 0.f, 0.f);
}

// convert edge indices AND count degrees (dst half) in one pass
__global__ void cvtdeg_kernel(const void* __restrict__ p, int* __restrict__ out,
                              int* __restrict__ deg, int E, const int* __restrict__ flag) {
    int i = blockIdx.x * blockDim.x + threadIdx.x;
    if (i < 2 * E) {
        int v = (*flag) ? (int)((const long long*)p)[i] : ((const int*)p)[i];
        out[i] = v;
        if (i >= E) atomicAdd(&deg[v], 1);
    }
}

// ---------------- x -> bf16, PRESCALED by dinv[node] (runs after scan3) ----------------
__global__ void cvtx_kernel(const float* __restrict__ x, const float* __restrict__ dinv,
                            unsigned short* __restrict__ xb, int n, int IN) {
    int i = blockIdx.x * blockDim.x + threadIdx.x;
    if (i < n) {
        int node = i / IN;
        xb[i] = f2bf(x[i] * dinv[node]);
    }
}

// ---------------- exclusive scan (3 kernels) ----------------
__global__ __launch_bounds__(SCAN_B) void scan1_kernel(const int* __restrict__ deg,
                                                       int* __restrict__ incl,
                                                       int* __restrict__ blockSums, int N) {
    __shared__ int s[SCAN_B];
    int i = blockIdx.x * SCAN_B + threadIdx.x;
    int v = (i < N) ? deg[i] : 0;
    s[threadIdx.x] = v;
    __syncthreads();
#pragma unroll
    for (int off = 1; off < SCAN_B; off <<= 1) {
        int t = (threadIdx.x >= off) ? s[threadIdx.x - off] : 0;
        __syncthreads();
        s[threadIdx.x] += t;
        __syncthreads();
    }
    if (i < N) incl[i] = s[threadIdx.x];
    if (threadIdx.x == SCAN_B - 1) blockSums[blockIdx.x] = s[SCAN_B - 1];
}

__global__ __launch_bounds__(1024) void scan2_kernel(int* __restrict__ blockSums, int nb) {
    __shared__ int s[1024];
    int v = (threadIdx.x < nb) ? blockSums[threadIdx.x] : 0;
    s[threadIdx.x] = v;
    __syncthreads();
#pragma unroll
    for (int off = 1; off < 1024; off <<= 1) {
        int t = (threadIdx.x >= off) ? s[threadIdx.x - off] : 0;
        __syncthreads();
        s[threadIdx.x] += t;
        __syncthreads();
    }
    if (threadIdx.x < nb) blockSums[threadIdx.x] = (threadIdx.x > 0) ? s[threadIdx.x - 1] : 0;
}

// rowstart + dinv + cursor=0 + gstart binary search, all in one pass
__global__ void scan3_kernel(const int* __restrict__ incl, const int* __restrict__ deg,
                             const int* __restrict__ blockSums, int* __restrict__ rowstart,
                             float* __restrict__ dinv, int* __restrict__ cursor,
                             const void* __restrict__ bt, const int* __restrict__ flag,
                             int* __restrict__ gstart, int G,
                             int N, int E) {
    int i = blockIdx.x * blockDim.x + threadIdx.x;
    if (i < N) {
        int d = deg[i];
        rowstart[i] = incl[i] - d + blockSums[i / SCAN_B];
        dinv[i] = rsqrtf((float)(d + 1));  // +1 self loop
        cursor[i] = 0;
    }
    if (i == 0) rowstart[N] = E;
    if (i <= G) {
        int is64 = *flag;
        int lo = 0, hi = N;
        while (lo < hi) {
            int mid = (lo + hi) >> 1;
            int v = is64 ? (int)((const long long*)bt)[mid] : ((const int*)bt)[mid];
            if (v < i) lo = mid + 1; else hi = mid;
        }
        gstart[i] = lo;
    }
}

// ---------------- counting-sort scatter: 1 edge/thread, 4-byte entries (src only) --------
// norm is folded into prescaled rows (dinv-prescale algebra); no dinv gathers here.
// NOTE (round 10/12 evidence): 4-edge/thread ILP -> 166us; 782-bucket 2-pass -> 376us.
__global__ void scatter_kernel(const int* __restrict__ src, const int* __restrict__ dst,
                               const int* __restrict__ rowstart, int* __restrict__ cursor,
                               int* __restrict__ elist, int E) {
    int e = blockIdx.x * blockDim.x + threadIdx.x;
    if (e >= E) return;
    int s = src[e], d = dst[e];
    int pos = rowstart[d] + atomicAdd(&cursor[d], 1);
    elist[pos] = s;
}

// ---------------- fused layer1: 20-dim agg of prescaled x' + linear + bias + relu -> bf16 ----
// z[n] = dinv[n] * (sum_src x'[src] + x'[n]),  x' = dinv*x (bf16)
__global__ __launch_bounds__(256) void agg_lin1_kernel(const unsigned int* __restrict__ xb32,
                                                       const float* __restrict__ W,
                                                       const float* __restrict__ b,
                                                       unsigned int* __restrict__ h1b,
                                                       const int* __restrict__ rowstart,
                                                       const int* __restrict__ elist,
                                                       const float* __restrict__ dinv,
                                                       int N, int IN) {
    __shared__ float Ws[20 * HID];   // 10 KB
    __shared__ float zs[8][20];
    const int tid = threadIdx.x;
    for (int i = tid; i < IN * HID; i += 256) Ws[i] = W[i];

    const int g      = tid >> 5;        // node slot 0..7
    const int lane32 = tid & 31;
    const int slot   = lane32 >> 4;     // 0/1 edge slot
    const int l      = lane32 & 15;     // lane in slot
    const int node   = blockIdx.x * 8 + g;
    const int half   = IN >> 1;         // 10 uints per row (IN even)
    const bool act   = (node < N) && (l < half);

    float accx = 0.f, accy = 0.f;
    if (node < N) {
        int beg = rowstart[node], end = rowstart[node + 1];
        int e = beg + slot;
        for (; e + 6 < end; e += 8) {   // this slot: edges e, e+2, e+4, e+6
            int s0 = elist[e];
            int s1 = elist[e + 2];
            int s2 = elist[e + 4];
            int s3 = elist[e + 6];
            unsigned int u0 = act ? xb32[(size_t)s0 * half + l] : 0u;
            unsigned int u1 = act ? xb32[(size_t)s1 * half + l] : 0u;
            unsigned int u2 = act ? xb32[(size_t)s2 * half + l] : 0u;
            unsigned int u3 = act ? xb32[(size_t)s3 * half + l] : 0u;
            accx += bf_lo(u0) + bf_lo(u1) + bf_lo(u2) + bf_lo(u3);
            accy += bf_hi(u0) + bf_hi(u1) + bf_hi(u2) + bf_hi(u3);
        }
        for (; e < end; e += 2) {
            int s0 = elist[e];
            unsigned int u0 = act ? xb32[(size_t)s0 * half + l] : 0u;
            accx += bf_lo(u0);
            accy += bf_hi(u0);
        }
    }
    // merge the two edge slots (lane ^ 16), register-only
    accx += __shfl_xor(accx, 16, 64);
    accy += __shfl_xor(accy, 16, 64);
    if (node < N && slot == 0 && l < half) {
        float di = dinv[node];
        unsigned int us = xb32[(size_t)node * half + l];   // self term: x'[node]
        zs[g][2 * l]     = di * (accx + bf_lo(us));
        zs[g][2 * l + 1] = di * (accy + bf_hi(us));
    }
    __syncthreads();

    if (node < N) {
        const int j = lane32;
        float4 acc4 = ((const float4*)b)[j];
        for (int k = 0; k < IN; ++k) {
            float zv = zs[g][k];
            float4 w = *(const float4*)&Ws[k * HID + j * 4];
            acc4.x += zv * w.x; acc4.y += zv * w.y;
            acc4.z += zv * w.z; acc4.w += zv * w.w;
        }
        acc4.x = fmaxf(acc4.x, 0.f); acc4.y = fmaxf(acc4.y, 0.f);
        acc4.z = fmaxf(acc4.z, 0.f); acc4.w = fmaxf(acc4.w, 0.f);
        uint2 st;
        st.x = (unsigned)f2bf(acc4.x) | ((unsigned)f2bf(acc4.y) << 16);
        st.y = (unsigned)f2bf(acc4.z) | ((unsigned)f2bf(acc4.w) << 16);
        ((uint2*)h1b)[(size_t)node * 32 + j] = st;
    }
}

// ---------------- linear2: tiled SGEMM, BF16 in, BF16 out PRESCALED by dinv[row] ---------
#define TBM 64
#define TBN 64
#define TBK 32
#define XLD (TBM + 4)

__global__ __launch_bounds__(256) void gemm128_kernel(const unsigned int* __restrict__ Ab,
                                                      const float* __restrict__ W,
                                                      const float* __restrict__ dinv,
                                                      unsigned short* __restrict__ Cb, int N) {
    __shared__ float xs[TBK][XLD];
    __shared__ float wsh[TBK][TBN + 4];
    const int tid = threadIdx.x;
    const int n0 = blockIdx.x * TBM;
    const int c0 = blockIdx.y * TBN;
    const int ng = tid >> 4;
    const int cg = tid & 15;
    const int anode = tid >> 2;   // 0..63
    const int af    = tid & 3;    // uint4 index over 32-k chunk (8 bf16 each)
    const int wk    = tid >> 4;
    const int wc    = tid & 15;

    const uint4* Av = (const uint4*)Ab;

    float acc[4][4] = {};

    for (int k0 = 0; k0 < HID; k0 += TBK) {
        {
            int gn = n0 + anode;
            uint4 u = make_uint4(0u, 0u, 0u, 0u);
            if (gn < N) u = Av[(size_t)gn * 16 + (k0 >> 3) + af];
            int kb = af * 8;
            xs[kb + 0][anode] = bf_lo(u.x);
            xs[kb + 1][anode] = bf_hi(u.x);
            xs[kb + 2][anode] = bf_lo(u.y);
            xs[kb + 3][anode] = bf_hi(u.y);
            xs[kb + 4][anode] = bf_lo(u.z);
            xs[kb + 5][anode] = bf_hi(u.z);
            xs[kb + 6][anode] = bf_lo(u.w);
            xs[kb + 7][anode] = bf_hi(u.w);
        }
#pragma unroll
        for (int r = 0; r < 2; ++r) {
            int kk = wk + r * 16;
            *(float4*)&wsh[kk][wc * 4] =
                *(const float4*)(W + (size_t)(k0 + kk) * HID + c0 + wc * 4);
        }
        __syncthreads();
#pragma unroll
        for (int kk = 0; kk < TBK; ++kk) {
            float a[4], b[4];
            *(float4*)a = *(const float4*)&xs[kk][ng * 4];
            *(float4*)b = *(const float4*)&wsh[kk][cg * 4];
#pragma unroll
            for (int m = 0; m < 4; ++m)
#pragma unroll
                for (int n = 0; n < 4; ++n) acc[m][n] += a[m] * b[n];
        }
        __syncthreads();
    }

#pragma unroll
    for (int m = 0; m < 4; ++m) {
        int gn = n0 + ng * 4 + m;
        if (gn < N) {
            float di = dinv[gn];
            ushort4 st;
            st.x = f2bf(acc[m][0] * di); st.y = f2bf(acc[m][1] * di);
            st.z = f2bf(acc[m][2] * di); st.w = f2bf(acc[m][3] * di);
            *(ushort4*)(Cb + (size_t)gn * HID + c0 + cg * 4) = st;
        }
    }
}

// ---------------- 128-dim CSR aggregation over prescaled BF16 rows, BF16 out --------------
// out[n] = relu(dinv[n] * (sum_src h2'[src] + h2'[n]) + bias)
__global__ __launch_bounds__(256) void csr_aggb_kernel(const unsigned short* __restrict__ h2b,
                                                       unsigned short* __restrict__ outb,
                                                       const int* __restrict__ rowstart,
                                                       const int* __restrict__ elist,
                                                       const float* __restrict__ dinv,
                                                       const float* __restrict__ bias,
                                                       int N) {
    int node = blockIdx.x * 16 + (threadIdx.x >> 4);
    if (node >= N) return;
    int q = threadIdx.x & 15;
    const uint4* hv = (const uint4*)h2b;
    float acc[8] = {};
    int beg = rowstart[node], end = rowstart[node + 1];
    int e = beg;
    for (; e + 3 < end; e += 4) {
        int s0 = elist[e];
        int s1 = elist[e + 1];
        int s2 = elist[e + 2];
        int s3 = elist[e + 3];
        uint4 a0 = hv[(size_t)s0 * 16 + q];
        uint4 a1 = hv[(size_t)s1 * 16 + q];
        uint4 a2 = hv[(size_t)s2 * 16 + q];
        uint4 a3 = hv[(size_t)s3 * 16 + q];
        acc[0] += bf_lo(a0.x) + bf_lo(a1.x) + bf_lo(a2.x) + bf_lo(a3.x);
        acc[1] += bf_hi(a0.x) + bf_hi(a1.x) + bf_hi(a2.x) + bf_hi(a3.x);
        acc[2] += bf_lo(a0.y) + bf_lo(a1.y) + bf_lo(a2.y) + bf_lo(a3.y);
        acc[3] += bf_hi(a0.y) + bf_hi(a1.y) + bf_hi(a2.y) + bf_hi(a3.y);
        acc[4] += bf_lo(a0.z) + bf_lo(a1.z) + bf_lo(a2.z) + bf_lo(a3.z);
        acc[5] += bf_hi(a0.z) + bf_hi(a1.z) + bf_hi(a2.z) + bf_hi(a3.z);
        acc[6] += bf_lo(a0.w) + bf_lo(a1.w) + bf_lo(a2.w) + bf_lo(a3.w);
        acc[7] += bf_hi(a0.w) + bf_hi(a1.w) + bf_hi(a2.w) + bf_hi(a3.w);
    }
    for (; e < end; ++e) {
        int s0 = elist[e];
        uint4 a0 = hv[(size_t)s0 * 16 + q];
        acc[0] += bf_lo(a0.x); acc[1] += bf_hi(a0.x);
        acc[2] += bf_lo(a0.y); acc[3] += bf_hi(a0.y);
        acc[4] += bf_lo(a0.z); acc[5] += bf_hi(a0.z);
        acc[6] += bf_lo(a0.w); acc[7] += bf_hi(a0.w);
    }
    float di = dinv[node];
    uint4 sv = hv[(size_t)node * 16 + q];
    float self[8] = { bf_lo(sv.x), bf_hi(sv.x), bf_lo(sv.y), bf_hi(sv.y),
                      bf_lo(sv.z), bf_hi(sv.z), bf_lo(sv.w), bf_hi(sv.w) };
    float4 b0 = ((const float4*)bias)[2 * q];
    float4 b1 = ((const float4*)bias)[2 * q + 1];
    float r[8];
    r[0] = fmaxf(di * (acc[0] + self[0]) + b0.x, 0.f);
    r[1] = fmaxf(di * (acc[1] + self[1]) + b0.y, 0.f);
    r[2] = fmaxf(di * (acc[2] + self[2]) + b0.z, 0.f);
    r[3] = fmaxf(di * (acc[3] + self[3]) + b0.w, 0.f);
    r[4] = fmaxf(di * (acc[4] + self[4]) + b1.x, 0.f);
    r[5] = fmaxf(di * (acc[5] + self[5]) + b1.y, 0.f);
    r[6] = fmaxf(di * (acc[6] + self[6]) + b1.z, 0.f);
    r[7] = fmaxf(di * (acc[7] + self[7]) + b1.w, 0.f);
    uint4 st;
    st.x = (unsigned)f2bf(r[0]) | ((unsigned)f2bf(r[1]) << 16);
    st.y = (unsigned)f2bf(r[2]) | ((unsigned)f2bf(r[3]) << 16);
    st.z = (unsigned)f2bf(r[4]) | ((unsigned)f2bf(r[5]) << 16);
    st.w = (unsigned)f2bf(r[6]) | ((unsigned)f2bf(r[7]) << 16);
    ((uint4*)outb)[(size_t)node * 16 + q] = st;
}

// ---------------- pooling: segmented over BF16 rows, 1024 threads ----------------
__global__ __launch_bounds__(1024) void pool2_kernel(const unsigned short* __restrict__ hb,
                                                     const int* __restrict__ gstart,
                                                     float* __restrict__ meanp, int G) {
    int g = blockIdx.x;
    int part = threadIdx.x >> 7;   // 0..7
    int j = threadIdx.x & 127;
    int beg = gstart[g], end = gstart[g + 1];
    float s = 0.f;
    for (int n = beg + part; n < end; n += 8)
        s += __uint_as_float(((unsigned)hb[(size_t)n * HID + j]) << 16);
    __shared__ float red[8][HID];
    red[part][j] = s;
    __syncthreads();
    if (part == 0) {
        float tot = 0.f;
#pragma unroll
        for (int r = 0; r < 8; ++r) tot += red[r][j];
        float c = (float)(end - beg);
        meanp[(size_t)g * HID + j] = tot / fmaxf(c, 1.f);
    }
}

// ---------------- classifier as tiled GEMM ----------------
#define CBM 64
#define CBN 64
#define CBK 32

__global__ __launch_bounds__(256) void clsgemm_kernel(const float* __restrict__ A,
                                                      const float* __restrict__ Bw,
                                                      const float* __restrict__ bc,
                                                      float* __restrict__ C,
                                                      int G, int OUT) {
    __shared__ float as[CBK][CBM + 4];
    __shared__ float bs[CBK][CBN + 4];
    const int tid = threadIdx.x;
    const int g0 = blockIdx.y * CBM;
    const int c0 = blockIdx.x * CBN;
    const int mg = tid >> 4;
    const int cg = tid & 15;
    const int arow = tid >> 3;
    const int af   = tid & 7;
    const int wk   = tid >> 4;
    const int wc   = tid & 15;

    float acc[4][4] = {};

    for (int k0 = 0; k0 < HID; k0 += CBK) {
#pragma unroll
        for (int r = 0; r < 2; ++r) {
            int row = arow + r * 32;
            int g = g0 + row;
            float4 v = make_float4(0.f, 0.f, 0.f, 0.f);
            if (g < G) v = *(const float4*)(A + (size_t)g * HID + k0 + af * 4);
            as[af * 4 + 0][row] = v.x;
            as[af * 4 + 1][row] = v.y;
            as[af * 4 + 2][row] = v.z;
            as[af * 4 + 3][row] = v.w;
        }
#pragma unroll
        for (int r = 0; r < 2; ++r) {
            int kk = wk + r * 16;
            int c = c0 + wc * 4;
            const float* bp = Bw + (size_t)(k0 + kk) * OUT + c;
            float2 lo = make_float2(0.f, 0.f), hi = make_float2(0.f, 0.f);
            if (c + 3 < OUT) {
                lo = *(const float2*)bp;
                hi = *(const float2*)(bp + 2);
            } else {
                if (c + 0 < OUT) lo.x = bp[0];
                if (c + 1 < OUT) lo.y = bp[1];
                if (c + 2 < OUT) hi.x = bp[2];
                if (c + 3 < OUT) hi.y = bp[3];
            }
            bs[kk][wc * 4 + 0] = lo.x;
            bs[kk][wc * 4 + 1] = lo.y;
            bs[kk][wc * 4 + 2] = hi.x;
            bs[kk][wc * 4 + 3] = hi.y;
        }
        __syncthreads();
#pragma unroll
        for (int kk = 0; kk < CBK; ++kk) {
            float a[4], b[4];
            *(float4*)a = *(const float4*)&as[kk][mg * 4];
            *(float4*)b = *(const float4*)&bs[kk][cg * 4];
#pragma unroll
            for (int m = 0; m < 4; ++m)
#pragma unroll
                for (int n = 0; n < 4; ++n) acc[m][n] += a[m] * b[n];
        }
        __syncthreads();
    }

    int c = c0 + cg * 4;
    float b0 = (c + 0 < OUT) ? bc[c + 0] : 0.f;
    float b1 = (c + 1 < OUT) ? bc[c + 1] : 0.f;
    float b2 = (c + 2 < OUT) ? bc[c + 2] : 0.f;
    float b3 = (c + 3 < OUT) ? bc[c + 3] : 0.f;
#pragma unroll
    for (int m = 0; m < 4; ++m) {
        int g = g0 + mg * 4 + m;
        if (g >= G) continue;
        float* cp = C + (size_t)g * OUT + c;
        if (c + 3 < OUT) {
            *(float2*)cp = make_float2(acc[m][0] + b0, acc[m][1] + b1);
            *(float2*)(cp + 2) = make_float2(acc[m][2] + b2, acc[m][3] + b3);
        } else {
            if (c + 0 < OUT) cp[0] = acc[m][0] + b0;
            if (c + 1 < OUT) cp[1] = acc[m][1] + b1;
            if (c + 2 < OUT) cp[2] = acc[m][2] + b2;
            if (c + 3 < OUT) cp[3] = acc[m][3] + b3;
        }
    }
}

// ---------------- launch ----------------
extern "C" void kernel_launch(void* const* d_in, const int* in_sizes, int n_in,
                              void* d_out, int out_size, void* d_ws, size_t ws_size,
                              hipStream_t stream) {
    const float* x  = (const float*)d_in[0];
    const void*  ei = d_in[1];
    const void*  bt = d_in[2];
    const float* W1 = (const float*)d_in[3];
    const float* b1 = (const float*)d_in[4];
    const float* W2 = (const float*)d_in[5];
    const float* b2 = (const float*)d_in[6];
    const float* Wc = (const float*)d_in[7];
    const float* bc = (const float*)d_in[8];
    float* out = (float*)d_out;

    const int N   = in_sizes[2];
    const int E   = in_sizes[1] / 2;
    const int IN  = in_sizes[0] / N;
    const int OUT = in_sizes[8];
    const int G   = out_size / OUT;

    char* ws = (char*)d_ws;
    size_t off = 0;
    auto alloc = [&](size_t bytes) {
        size_t p = off;
        off += (bytes + 255) & ~(size_t)255;
        return p;
    };
    int*            idx32    = (int*)(ws + alloc((size_t)2 * E * 4));
    int*            deg      = (int*)(ws + alloc((size_t)N * 4));
    float*          dinv     = (float*)(ws + alloc((size_t)N * 4));
    int*            incl     = (int*)(ws + alloc((size_t)N * 4));
    int*            rowstart = (int*)(ws + alloc((size_t)(N + 1) * 4));
    int*            cursor   = (int*)(ws + alloc((size_t)N * 4));
    int*            blockSums= (int*)(ws + alloc((size_t)1024 * 4));
    int*            elist    = (int*)(ws + alloc((size_t)E * 4));
    unsigned short* xb       = (unsigned short*)(ws + alloc((size_t)N * IN * 2));
    unsigned int*   h1b      = (unsigned int*)(ws + alloc((size_t)N * HID * 2));
    unsigned short* h2b      = (unsigned short*)(ws + alloc((size_t)N * HID * 2));
    unsigned short* houtb    = (unsigned short*)(ws + alloc((size_t)N * HID * 2));
    int*            gstart   = (int*)(ws + alloc((size_t)(G + 1) * 4));
    float*          meanp    = (float*)(ws + alloc((size_t)G * HID * 4));
    int*            flag     = (int*)(ws + alloc(4));
    (void)ws_size;

    int* srcI = idx32;
    int* dstI = idx32 + E;

    const int B = 256;
    const int nb = (N + SCAN_B - 1) / SCAN_B;

    // 1. detect dtype + zero deg (fused); convert edges (+degree count)
    init_kernel<<<256, B, 0, stream>>>((const unsigned int*)ei, flag, (float4*)deg,
                                       (long long)N / 4);
    cvtdeg_kernel<<<(2 * E + B - 1) / B, B, 0, stream>>>(ei, idx32, deg, E, flag);

    // 2. CSR build: scan (+dinv +cursor=0 +gstart); x -> prescaled bf16; scatter (src only)
    scan1_kernel<<<nb, SCAN_B, 0, stream>>>(deg, incl, blockSums, N);
    scan2_kernel<<<1, 1024, 0, stream>>>(blockSums, nb);
    scan3_kernel<<<(N + B - 1) / B, B, 0, stream>>>(incl, deg, blockSums, rowstart,
                                                    dinv, cursor, bt, flag, gstart, G, N, E);
    cvtx_kernel<<<(N * IN + B - 1) / B, B, 0, stream>>>(x, dinv, xb, N * IN, IN);
    scatter_kernel<<<(E + B - 1) / B, B, 0, stream>>>(srcI, dstI, rowstart, cursor, elist, E);

    // 3. layer 1: fused input-space agg (prescaled) + linear + bias + relu -> bf16
    agg_lin1_kernel<<<(N + 7) / 8, 256, 0, stream>>>((const unsigned int*)xb, W1, b1,
                                                     h1b, rowstart, elist, dinv, N, IN);

    // 4. layer 2: GEMM (bf16 in, prescaled bf16 out) then aggregation -> bf16
    {
        dim3 grid((N + TBM - 1) / TBM, HID / TBN);
        gemm128_kernel<<<grid, 256, 0, stream>>>(h1b, W2, dinv, h2b, N);
    }
    csr_aggb_kernel<<<(N + 15) / 16, 256, 0, stream>>>(h2b, houtb, rowstart, elist, dinv, b2, N);

    // 5. mean pool (segmented, bf16 input)
    pool2_kernel<<<G, 1024, 0, stream>>>(houtb, gstart, meanp, G);

    // 6. classifier GEMM
    {
        dim3 grid((OUT + CBN - 1) / CBN, (G + CBM - 1) / CBM);
        clsgemm_kernel<<<grid, 256, 0, stream>>>(meanp, Wc, bc, out, G, OUT);
    }
}

// Round 15
// 371.464 us; speedup vs baseline: 1.0533x; 1.0533x over previous
//
#include <hip/hip_runtime.h>

#define HID 128
#define SCAN_B 256

__device__ __forceinline__ float bf_lo(unsigned int u) { return __uint_as_float(u << 16); }
__device__ __forceinline__ float bf_hi(unsigned int u) { return __uint_as_float(u & 0xFFFF0000u); }
__device__ __forceinline__ unsigned short f2bf(float f) {
    unsigned int u = __float_as_uint(f);
    unsigned int r = (u + 0x7FFFu + ((u >> 16) & 1u)) >> 16;
    return (unsigned short)r;
}

// ---------------- init: detect index dtype (1 thread) + zero deg (grid-stride) ----------
__global__ void init_kernel(const unsigned int* __restrict__ p, int* __restrict__ flag,
                            float4* __restrict__ deg4, long long n4) {
    if (blockIdx.x == 0 && threadIdx.x == 0) {
        int is64 = 1;
        for (int i = 0; i < 64; ++i) {
            if (p[2 * i + 1] != 0u) { is64 = 0; break; }
        }
        *flag = is64;
    }
    long long i = (long long)blockIdx.x * blockDim.x + threadIdx.x;
    long long stride = (long long)gridDim.x * blockDim.x;
    for (; i < n4; i += stride) deg4[i] = make_float4(0.f, 0.f, 0.f, 0.f);
}

// convert edge indices AND count degrees (dst half) in one pass
__global__ void cvtdeg_kernel(const void* __restrict__ p, int* __restrict__ out,
                              int* __restrict__ deg, int E, const int* __restrict__ flag) {
    int i = blockIdx.x * blockDim.x + threadIdx.x;
    if (i < 2 * E) {
        int v = (*flag) ? (int)((const long long*)p)[i] : ((const int*)p)[i];
        out[i] = v;
        if (i >= E) atomicAdd(&deg[v], 1);
    }
}

// ---------------- x -> bf16, PRESCALED by dinv[node] (runs after scan3) ----------------
__global__ void cvtx_kernel(const float* __restrict__ x, const float* __restrict__ dinv,
                            unsigned short* __restrict__ xb, int n, int IN) {
    int i = blockIdx.x * blockDim.x + threadIdx.x;
    if (i < n) {
        int node = i / IN;
        xb[i] = f2bf(x[i] * dinv[node]);
    }
}

// ---------------- exclusive scan (3 kernels) ----------------
__global__ __launch_bounds__(SCAN_B) void scan1_kernel(const int* __restrict__ deg,
                                                       int* __restrict__ incl,
                                                       int* __restrict__ blockSums, int N) {
    __shared__ int s[SCAN_B];
    int i = blockIdx.x * SCAN_B + threadIdx.x;
    int v = (i < N) ? deg[i] : 0;
    s[threadIdx.x] = v;
    __syncthreads();
#pragma unroll
    for (int off = 1; off < SCAN_B; off <<= 1) {
        int t = (threadIdx.x >= off) ? s[threadIdx.x - off] : 0;
        __syncthreads();
        s[threadIdx.x] += t;
        __syncthreads();
    }
    if (i < N) incl[i] = s[threadIdx.x];
    if (threadIdx.x == SCAN_B - 1) blockSums[blockIdx.x] = s[SCAN_B - 1];
}

__global__ __launch_bounds__(1024) void scan2_kernel(int* __restrict__ blockSums, int nb) {
    __shared__ int s[1024];
    int v = (threadIdx.x < nb) ? blockSums[threadIdx.x] : 0;
    s[threadIdx.x] = v;
    __syncthreads();
#pragma unroll
    for (int off = 1; off < 1024; off <<= 1) {
        int t = (threadIdx.x >= off) ? s[threadIdx.x - off] : 0;
        __syncthreads();
        s[threadIdx.x] += t;
        __syncthreads();
    }
    if (threadIdx.x < nb) blockSums[threadIdx.x] = (threadIdx.x > 0) ? s[threadIdx.x - 1] : 0;
}

// rowstart + dinv + cursor=0 + gstart binary search, all in one pass
__global__ void scan3_kernel(const int* __restrict__ incl, const int* __restrict__ deg,
                             const int* __restrict__ blockSums, int* __restrict__ rowstart,
                             float* __restrict__ dinv, int* __restrict__ cursor,
                             const void* __restrict__ bt, const int* __restrict__ flag,
                             int* __restrict__ gstart, int G,
                             int N, int E) {
    int i = blockIdx.x * blockDim.x + threadIdx.x;
    if (i < N) {
        int d = deg[i];
        rowstart[i] = incl[i] - d + blockSums[i / SCAN_B];
        dinv[i] = rsqrtf((float)(d + 1));  // +1 self loop
        cursor[i] = 0;
    }
    if (i == 0) rowstart[N] = E;
    if (i <= G) {
        int is64 = *flag;
        int lo = 0, hi = N;
        while (lo < hi) {
            int mid = (lo + hi) >> 1;
            int v = is64 ? (int)((const long long*)bt)[mid] : ((const int*)bt)[mid];
            if (v < i) lo = mid + 1; else hi = mid;
        }
        gstart[i] = lo;
    }
}

// ---------------- counting-sort scatter: EXACT round-13 body (72us proven) ----------------
// 8-byte entries; .y (norm) is unused by prescaled consumers but 8B stores are measurably
// faster than 4B random stores (round 14: 4B entries -> 118us, +65%). Do not "slim" this.
__global__ void scatter_kernel(const int* __restrict__ src, const int* __restrict__ dst,
                               const int* __restrict__ rowstart, int* __restrict__ cursor,
                               int2* __restrict__ elist, const float* __restrict__ dinv, int E) {
    int e = blockIdx.x * blockDim.x + threadIdx.x;
    if (e >= E) return;
    int s = src[e], d = dst[e];
    int pos = rowstart[d] + atomicAdd(&cursor[d], 1);
    float nm = dinv[s] * dinv[d];
    elist[pos] = make_int2(s, __float_as_int(nm));
}

// ---------------- fused layer1: 20-dim agg of prescaled x' + linear + bias + relu -> bf16 ----
// z[n] = dinv[n] * (sum_src x'[src] + x'[n]),  x' = dinv*x (bf16)
__global__ __launch_bounds__(256) void agg_lin1_kernel(const unsigned int* __restrict__ xb32,
                                                       const float* __restrict__ W,
                                                       const float* __restrict__ b,
                                                       unsigned int* __restrict__ h1b,
                                                       const int* __restrict__ rowstart,
                                                       const int2* __restrict__ elist,
                                                       const float* __restrict__ dinv,
                                                       int N, int IN) {
    __shared__ float Ws[20 * HID];   // 10 KB
    __shared__ float zs[8][20];
    const int tid = threadIdx.x;
    for (int i = tid; i < IN * HID; i += 256) Ws[i] = W[i];

    const int g      = tid >> 5;        // node slot 0..7
    const int lane32 = tid & 31;
    const int slot   = lane32 >> 4;     // 0/1 edge slot
    const int l      = lane32 & 15;     // lane in slot
    const int node   = blockIdx.x * 8 + g;
    const int half   = IN >> 1;         // 10 uints per row (IN even)
    const bool act   = (node < N) && (l < half);

    float accx = 0.f, accy = 0.f;
    if (node < N) {
        int beg = rowstart[node], end = rowstart[node + 1];
        int e = beg + slot;
        for (; e + 6 < end; e += 8) {   // this slot: edges e, e+2, e+4, e+6
            int s0 = elist[e].x;
            int s1 = elist[e + 2].x;
            int s2 = elist[e + 4].x;
            int s3 = elist[e + 6].x;
            unsigned int u0 = act ? xb32[(size_t)s0 * half + l] : 0u;
            unsigned int u1 = act ? xb32[(size_t)s1 * half + l] : 0u;
            unsigned int u2 = act ? xb32[(size_t)s2 * half + l] : 0u;
            unsigned int u3 = act ? xb32[(size_t)s3 * half + l] : 0u;
            accx += bf_lo(u0) + bf_lo(u1) + bf_lo(u2) + bf_lo(u3);
            accy += bf_hi(u0) + bf_hi(u1) + bf_hi(u2) + bf_hi(u3);
        }
        for (; e < end; e += 2) {
            int s0 = elist[e].x;
            unsigned int u0 = act ? xb32[(size_t)s0 * half + l] : 0u;
            accx += bf_lo(u0);
            accy += bf_hi(u0);
        }
    }
    // merge the two edge slots (lane ^ 16), register-only
    accx += __shfl_xor(accx, 16, 64);
    accy += __shfl_xor(accy, 16, 64);
    if (node < N && slot == 0 && l < half) {
        float di = dinv[node];
        unsigned int us = xb32[(size_t)node * half + l];   // self term: x'[node]
        zs[g][2 * l]     = di * (accx + bf_lo(us));
        zs[g][2 * l + 1] = di * (accy + bf_hi(us));
    }
    __syncthreads();

    if (node < N) {
        const int j = lane32;
        float4 acc4 = ((const float4*)b)[j];
        for (int k = 0; k < IN; ++k) {
            float zv = zs[g][k];
            float4 w = *(const float4*)&Ws[k * HID + j * 4];
            acc4.x += zv * w.x; acc4.y += zv * w.y;
            acc4.z += zv * w.z; acc4.w += zv * w.w;
        }
        acc4.x = fmaxf(acc4.x, 0.f); acc4.y = fmaxf(acc4.y, 0.f);
        acc4.z = fmaxf(acc4.z, 0.f); acc4.w = fmaxf(acc4.w, 0.f);
        uint2 st;
        st.x = (unsigned)f2bf(acc4.x) | ((unsigned)f2bf(acc4.y) << 16);
        st.y = (unsigned)f2bf(acc4.z) | ((unsigned)f2bf(acc4.w) << 16);
        ((uint2*)h1b)[(size_t)node * 32 + j] = st;
    }
}

// ---------------- linear2: tiled SGEMM, BF16 in, BF16 out PRESCALED by dinv[row] ---------
#define TBM 64
#define TBN 64
#define TBK 32
#define XLD (TBM + 4)

__global__ __launch_bounds__(256) void gemm128_kernel(const unsigned int* __restrict__ Ab,
                                                      const float* __restrict__ W,
                                                      const float* __restrict__ dinv,
                                                      unsigned short* __restrict__ Cb, int N) {
    __shared__ float xs[TBK][XLD];
    __shared__ float wsh[TBK][TBN + 4];
    const int tid = threadIdx.x;
    const int n0 = blockIdx.x * TBM;
    const int c0 = blockIdx.y * TBN;
    const int ng = tid >> 4;
    const int cg = tid & 15;
    const int anode = tid >> 2;   // 0..63
    const int af    = tid & 3;    // uint4 index over 32-k chunk (8 bf16 each)
    const int wk    = tid >> 4;
    const int wc    = tid & 15;

    const uint4* Av = (const uint4*)Ab;

    float acc[4][4] = {};

    for (int k0 = 0; k0 < HID; k0 += TBK) {
        {
            int gn = n0 + anode;
            uint4 u = make_uint4(0u, 0u, 0u, 0u);
            if (gn < N) u = Av[(size_t)gn * 16 + (k0 >> 3) + af];
            int kb = af * 8;
            xs[kb + 0][anode] = bf_lo(u.x);
            xs[kb + 1][anode] = bf_hi(u.x);
            xs[kb + 2][anode] = bf_lo(u.y);
            xs[kb + 3][anode] = bf_hi(u.y);
            xs[kb + 4][anode] = bf_lo(u.z);
            xs[kb + 5][anode] = bf_hi(u.z);
            xs[kb + 6][anode] = bf_lo(u.w);
            xs[kb + 7][anode] = bf_hi(u.w);
        }
#pragma unroll
        for (int r = 0; r < 2; ++r) {
            int kk = wk + r * 16;
            *(float4*)&wsh[kk][wc * 4] =
                *(const float4*)(W + (size_t)(k0 + kk) * HID + c0 + wc * 4);
        }
        __syncthreads();
#pragma unroll
        for (int kk = 0; kk < TBK; ++kk) {
            float a[4], b[4];
            *(float4*)a = *(const float4*)&xs[kk][ng * 4];
            *(float4*)b = *(const float4*)&wsh[kk][cg * 4];
#pragma unroll
            for (int m = 0; m < 4; ++m)
#pragma unroll
                for (int n = 0; n < 4; ++n) acc[m][n] += a[m] * b[n];
        }
        __syncthreads();
    }

#pragma unroll
    for (int m = 0; m < 4; ++m) {
        int gn = n0 + ng * 4 + m;
        if (gn < N) {
            float di = dinv[gn];
            ushort4 st;
            st.x = f2bf(acc[m][0] * di); st.y = f2bf(acc[m][1] * di);
            st.z = f2bf(acc[m][2] * di); st.w = f2bf(acc[m][3] * di);
            *(ushort4*)(Cb + (size_t)gn * HID + c0 + cg * 4) = st;
        }
    }
}

// ---------------- 128-dim CSR aggregation over prescaled BF16 rows, BF16 out --------------
// out[n] = relu(dinv[n] * (sum_src h2'[src] + h2'[n]) + bias)
__global__ __launch_bounds__(256) void csr_aggb_kernel(const unsigned short* __restrict__ h2b,
                                                       unsigned short* __restrict__ outb,
                                                       const int* __restrict__ rowstart,
                                                       const int2* __restrict__ elist,
                                                       const float* __restrict__ dinv,
                                                       const float* __restrict__ bias,
                                                       int N) {
    int node = blockIdx.x * 16 + (threadIdx.x >> 4);
    if (node >= N) return;
    int q = threadIdx.x & 15;
    const uint4* hv = (const uint4*)h2b;
    float acc[8] = {};
    int beg = rowstart[node], end = rowstart[node + 1];
    int e = beg;
    for (; e + 3 < end; e += 4) {
        int s0 = elist[e].x;
        int s1 = elist[e + 1].x;
        int s2 = elist[e + 2].x;
        int s3 = elist[e + 3].x;
        uint4 a0 = hv[(size_t)s0 * 16 + q];
        uint4 a1 = hv[(size_t)s1 * 16 + q];
        uint4 a2 = hv[(size_t)s2 * 16 + q];
        uint4 a3 = hv[(size_t)s3 * 16 + q];
        acc[0] += bf_lo(a0.x) + bf_lo(a1.x) + bf_lo(a2.x) + bf_lo(a3.x);
        acc[1] += bf_hi(a0.x) + bf_hi(a1.x) + bf_hi(a2.x) + bf_hi(a3.x);
        acc[2] += bf_lo(a0.y) + bf_lo(a1.y) + bf_lo(a2.y) + bf_lo(a3.y);
        acc[3] += bf_hi(a0.y) + bf_hi(a1.y) + bf_hi(a2.y) + bf_hi(a3.y);
        acc[4] += bf_lo(a0.z) + bf_lo(a1.z) + bf_lo(a2.z) + bf_lo(a3.z);
        acc[5] += bf_hi(a0.z) + bf_hi(a1.z) + bf_hi(a2.z) + bf_hi(a3.z);
        acc[6] += bf_lo(a0.w) + bf_lo(a1.w) + bf_lo(a2.w) + bf_lo(a3.w);
        acc[7] += bf_hi(a0.w) + bf_hi(a1.w) + bf_hi(a2.w) + bf_hi(a3.w);
    }
    for (; e < end; ++e) {
        int s0 = elist[e].x;
        uint4 a0 = hv[(size_t)s0 * 16 + q];
        acc[0] += bf_lo(a0.x); acc[1] += bf_hi(a0.x);
        acc[2] += bf_lo(a0.y); acc[3] += bf_hi(a0.y);
        acc[4] += bf_lo(a0.z); acc[5] += bf_hi(a0.z);
        acc[6] += bf_lo(a0.w); acc[7] += bf_hi(a0.w);
    }
    float di = dinv[node];
    uint4 sv = hv[(size_t)node * 16 + q];
    float self[8] = { bf_lo(sv.x), bf_hi(sv.x), bf_lo(sv.y), bf_hi(sv.y),
                      bf_lo(sv.z), bf_hi(sv.z), bf_lo(sv.w), bf_hi(sv.w) };
    float4 b0 = ((const float4*)bias)[2 * q];
    float4 b1 = ((const float4*)bias)[2 * q + 1];
    float r[8];
    r[0] = fmaxf(di * (acc[0] + self[0]) + b0.x, 0.f);
    r[1] = fmaxf(di * (acc[1] + self[1]) + b0.y, 0.f);
    r[2] = fmaxf(di * (acc[2] + self[2]) + b0.z, 0.f);
    r[3] = fmaxf(di * (acc[3] + self[3]) + b0.w, 0.f);
    r[4] = fmaxf(di * (acc[4] + self[4]) + b1.x, 0.f);
    r[5] = fmaxf(di * (acc[5] + self[5]) + b1.y, 0.f);
    r[6] = fmaxf(di * (acc[6] + self[6]) + b1.z, 0.f);
    r[7] = fmaxf(di * (acc[7] + self[7]) + b1.w, 0.f);
    uint4 st;
    st.x = (unsigned)f2bf(r[0]) | ((unsigned)f2bf(r[1]) << 16);
    st.y = (unsigned)f2bf(r[2]) | ((unsigned)f2bf(r[3]) << 16);
    st.z = (unsigned)f2bf(r[4]) | ((unsigned)f2bf(r[5]) << 16);
    st.w = (unsigned)f2bf(r[6]) | ((unsigned)f2bf(r[7]) << 16);
    ((uint4*)outb)[(size_t)node * 16 + q] = st;
}

// ---------------- pooling: segmented over BF16 rows, 1024 threads ----------------
__global__ __launch_bounds__(1024) void pool2_kernel(const unsigned short* __restrict__ hb,
                                                     const int* __restrict__ gstart,
                                                     float* __restrict__ meanp, int G) {
    int g = blockIdx.x;
    int part = threadIdx.x >> 7;   // 0..7
    int j = threadIdx.x & 127;
    int beg = gstart[g], end = gstart[g + 1];
    float s = 0.f;
    for (int n = beg + part; n < end; n += 8)
        s += __uint_as_float(((unsigned)hb[(size_t)n * HID + j]) << 16);
    __shared__ float red[8][HID];
    red[part][j] = s;
    __syncthreads();
    if (part == 0) {
        float tot = 0.f;
#pragma unroll
        for (int r = 0; r < 8; ++r) tot += red[r][j];
        float c = (float)(end - beg);
        meanp[(size_t)g * HID + j] = tot / fmaxf(c, 1.f);
    }
}

// ---------------- classifier as tiled GEMM ----------------
#define CBM 64
#define CBN 64
#define CBK 32

__global__ __launch_bounds__(256) void clsgemm_kernel(const float* __restrict__ A,
                                                      const float* __restrict__ Bw,
                                                      const float* __restrict__ bc,
                                                      float* __restrict__ C,
                                                      int G, int OUT) {
    __shared__ float as[CBK][CBM + 4];
    __shared__ float bs[CBK][CBN + 4];
    const int tid = threadIdx.x;
    const int g0 = blockIdx.y * CBM;
    const int c0 = blockIdx.x * CBN;
    const int mg = tid >> 4;
    const int cg = tid & 15;
    const int arow = tid >> 3;
    const int af   = tid & 7;
    const int wk   = tid >> 4;
    const int wc   = tid & 15;

    float acc[4][4] = {};

    for (int k0 = 0; k0 < HID; k0 += CBK) {
#pragma unroll
        for (int r = 0; r < 2; ++r) {
            int row = arow + r * 32;
            int g = g0 + row;
            float4 v = make_float4(0.f, 0.f, 0.f, 0.f);
            if (g < G) v = *(const float4*)(A + (size_t)g * HID + k0 + af * 4);
            as[af * 4 + 0][row] = v.x;
            as[af * 4 + 1][row] = v.y;
            as[af * 4 + 2][row] = v.z;
            as[af * 4 + 3][row] = v.w;
        }
#pragma unroll
        for (int r = 0; r < 2; ++r) {
            int kk = wk + r * 16;
            int c = c0 + wc * 4;
            const float* bp = Bw + (size_t)(k0 + kk) * OUT + c;
            float2 lo = make_float2(0.f, 0.f), hi = make_float2(0.f, 0.f);
            if (c + 3 < OUT) {
                lo = *(const float2*)bp;
                hi = *(const float2*)(bp + 2);
            } else {
                if (c + 0 < OUT) lo.x = bp[0];
                if (c + 1 < OUT) lo.y = bp[1];
                if (c + 2 < OUT) hi.x = bp[2];
                if (c + 3 < OUT) hi.y = bp[3];
            }
            bs[kk][wc * 4 + 0] = lo.x;
            bs[kk][wc * 4 + 1] = lo.y;
            bs[kk][wc * 4 + 2] = hi.x;
            bs[kk][wc * 4 + 3] = hi.y;
        }
        __syncthreads();
#pragma unroll
        for (int kk = 0; kk < CBK; ++kk) {
            float a[4], b[4];
            *(float4*)a = *(const float4*)&as[kk][mg * 4];
            *(float4*)b = *(const float4*)&bs[kk][cg * 4];
#pragma unroll
            for (int m = 0; m < 4; ++m)
#pragma unroll
                for (int n = 0; n < 4; ++n) acc[m][n] += a[m] * b[n];
        }
        __syncthreads();
    }

    int c = c0 + cg * 4;
    float b0 = (c + 0 < OUT) ? bc[c + 0] : 0.f;
    float b1 = (c + 1 < OUT) ? bc[c + 1] : 0.f;
    float b2 = (c + 2 < OUT) ? bc[c + 2] : 0.f;
    float b3 = (c + 3 < OUT) ? bc[c + 3] : 0.f;
#pragma unroll
    for (int m = 0; m < 4; ++m) {
        int g = g0 + mg * 4 + m;
        if (g >= G) continue;
        float* cp = C + (size_t)g * OUT + c;
        if (c + 3 < OUT) {
            *(float2*)cp = make_float2(acc[m][0] + b0, acc[m][1] + b1);
            *(float2*)(cp + 2) = make_float2(acc[m][2] + b2, acc[m][3] + b3);
        } else {
            if (c + 0 < OUT) cp[0] = acc[m][0] + b0;
            if (c + 1 < OUT) cp[1] = acc[m][1] + b1;
            if (c + 2 < OUT) cp[2] = acc[m][2] + b2;
            if (c + 3 < OUT) cp[3] = acc[m][3] + b3;
        }
    }
}

// ---------------- launch ----------------
extern "C" void kernel_launch(void* const* d_in, const int* in_sizes, int n_in,
                              void* d_out, int out_size, void* d_ws, size_t ws_size,
                              hipStream_t stream) {
    const float* x  = (const float*)d_in[0];
    const void*  ei = d_in[1];
    const void*  bt = d_in[2];
    const float* W1 = (const float*)d_in[3];
    const float* b1 = (const float*)d_in[4];
    const float* W2 = (const float*)d_in[5];
    const float* b2 = (const float*)d_in[6];
    const float* Wc = (const float*)d_in[7];
    const float* bc = (const float*)d_in[8];
    float* out = (float*)d_out;

    const int N   = in_sizes[2];
    const int E   = in_sizes[1] / 2;
    const int IN  = in_sizes[0] / N;
    const int OUT = in_sizes[8];
    const int G   = out_size / OUT;

    char* ws = (char*)d_ws;
    size_t off = 0;
    auto alloc = [&](size_t bytes) {
        size_t p = off;
        off += (bytes + 255) & ~(size_t)255;
        return p;
    };
    int*            idx32    = (int*)(ws + alloc((size_t)2 * E * 4));
    int*            deg      = (int*)(ws + alloc((size_t)N * 4));
    float*          dinv     = (float*)(ws + alloc((size_t)N * 4));
    int*            incl     = (int*)(ws + alloc((size_t)N * 4));
    int*            rowstart = (int*)(ws + alloc((size_t)(N + 1) * 4));
    int*            cursor   = (int*)(ws + alloc((size_t)N * 4));
    int*            blockSums= (int*)(ws + alloc((size_t)1024 * 4));
    int2*           elist    = (int2*)(ws + alloc((size_t)E * 8));
    unsigned short* xb       = (unsigned short*)(ws + alloc((size_t)N * IN * 2));
    unsigned int*   h1b      = (unsigned int*)(ws + alloc((size_t)N * HID * 2));
    unsigned short* h2b      = (unsigned short*)(ws + alloc((size_t)N * HID * 2));
    unsigned short* houtb    = (unsigned short*)(ws + alloc((size_t)N * HID * 2));
    int*            gstart   = (int*)(ws + alloc((size_t)(G + 1) * 4));
    float*          meanp    = (float*)(ws + alloc((size_t)G * HID * 4));
    int*            flag     = (int*)(ws + alloc(4));
    (void)ws_size;

    int* srcI = idx32;
    int* dstI = idx32 + E;

    const int B = 256;
    const int nb = (N + SCAN_B - 1) / SCAN_B;

    // 1. detect dtype + zero deg (fused); convert edges (+degree count)
    init_kernel<<<256, B, 0, stream>>>((const unsigned int*)ei, flag, (float4*)deg,
                                       (long long)N / 4);
    cvtdeg_kernel<<<(2 * E + B - 1) / B, B, 0, stream>>>(ei, idx32, deg, E, flag);

    // 2. CSR build: scan (+dinv +cursor=0 +gstart); x -> prescaled bf16; scatter (r13 body)
    scan1_kernel<<<nb, SCAN_B, 0, stream>>>(deg, incl, blockSums, N);
    scan2_kernel<<<1, 1024, 0, stream>>>(blockSums, nb);
    scan3_kernel<<<(N + B - 1) / B, B, 0, stream>>>(incl, deg, blockSums, rowstart,
                                                    dinv, cursor, bt, flag, gstart, G, N, E);
    cvtx_kernel<<<(N * IN + B - 1) / B, B, 0, stream>>>(x, dinv, xb, N * IN, IN);
    scatter_kernel<<<(E + B - 1) / B, B, 0, stream>>>(srcI, dstI, rowstart, cursor, elist, dinv, E);

    // 3. layer 1: fused input-space agg (prescaled) + linear + bias + relu -> bf16
    agg_lin1_kernel<<<(N + 7) / 8, 256, 0, stream>>>((const unsigned int*)xb, W1, b1,
                                                     h1b, rowstart, elist, dinv, N, IN);

    // 4. layer 2: GEMM (bf16 in, prescaled bf16 out) then aggregation -> bf16
    {
        dim3 grid((N + TBM - 1) / TBM, HID / TBN);
        gemm128_kernel<<<grid, 256, 0, stream>>>(h1b, W2, dinv, h2b, N);
    }
    csr_aggb_kernel<<<(N + 15) / 16, 256, 0, stream>>>(h2b, houtb, rowstart, elist, dinv, b2, N);

    // 5. mean pool (segmented, bf16 input)
    pool2_kernel<<<G, 1024, 0, stream>>>(houtb, gstart, meanp, G);

    // 6. classifier GEMM
    {
        dim3 grid((OUT + CBN - 1) / CBN, (G + CBM - 1) / CBM);
        clsgemm_kernel<<<grid, 256, 0, stream>>>(meanp, Wc, bc, out, G, OUT);
    }
}